// Round 12
// baseline (18261.261 us; speedup 1.0000x reference)
//
#include <hip/hip_runtime.h>
#include <hip/hip_bf16.h>
#include <stdint.h>

#define B_ 128
#define T_ 256
#define S_ 256
#define I_ 512
#define H_ 512
#define CSLOT 4   // channel ring depth (intra-cluster drift <= 1 step => safe)

typedef __attribute__((ext_vector_type(8))) short short8;
typedef __attribute__((ext_vector_type(4))) float f32x4;
typedef unsigned short ushort_t;
typedef unsigned long long u64;
typedef unsigned int u32;

__device__ __forceinline__ float bf2f(ushort_t u){
  union{ u32 i; float f;} v; v.i = ((u32)u)<<16; return v.f;
}
__device__ __forceinline__ ushort_t f2bf(float f){
  union{ u32 i; float f;} v; v.f=f;
  u32 x=v.i; u32 r = x + 0x7fffu + ((x>>16)&1u);
  return (ushort_t)(r>>16);
}
__device__ __forceinline__ float sigm(float x){ return 1.f/(1.f + __expf(-x)); }
__device__ __forceinline__ float tanh_s(float x){
  float a = fabsf(x);
  float e = __expf(-2.f*a);
  float t = (1.f - e)/(1.f + e);
  return x < 0.f ? -t : t;
}

__device__ __forceinline__ f32x4 MFMA16(short8 a, short8 b, f32x4 c){
  typedef __attribute__((ext_vector_type(8))) __bf16 bf16x8;
  return __builtin_amdgcn_mfma_f32_16x16x32_bf16(
      __builtin_bit_cast(bf16x8, a), __builtin_bit_cast(bf16x8, b), c, 0, 0, 0);
}

// tagged channel primitives: (tag<<32)|payload in ONE atomic word
__device__ __forceinline__ void ch_st(u64* p, u32 tag, u32 payload){
  __hip_atomic_store(p, ((u64)tag << 32) | payload,
                     __ATOMIC_RELAXED, __HIP_MEMORY_SCOPE_AGENT);
}
__device__ __forceinline__ u64 ch_ld(const u64* p){
  return __hip_atomic_load(p, __ATOMIC_RELAXED, __HIP_MEMORY_SCOPE_AGENT);
}
// canary poll: LONG backoff (only few threads/block ever run this)
__device__ __forceinline__ void can_poll(const u64* p, u32 tag){
  u64 w = ch_ld(p);
  while ((u32)(w >> 32) != tag){
    __builtin_amdgcn_s_sleep(32);
    w = ch_ld(p);
  }
}
// one-shot data read with verify (rare retry; canary already confirmed producer done)
__device__ __forceinline__ u32 ch_read(const u64* p, u32 tag){
  u64 w = ch_ld(p);
  while ((u32)(w >> 32) != tag){
    __builtin_amdgcn_s_sleep(16);
    w = ch_ld(p);
  }
  return (u32)w;
}

// ---------------- converts / init ----------------

__global__ void k_cvt_bf16(const float* __restrict__ src, ushort_t* __restrict__ dst, int n){
  int i = (blockIdx.x*blockDim.x + threadIdx.x)*4;
  int stride = gridDim.x*blockDim.x*4;
  for (; i < n; i += stride){
    float4 v = *(const float4*)(src + i);
    ushort4 o; o.x=f2bf(v.x); o.y=f2bf(v.y); o.z=f2bf(v.z); o.w=f2bf(v.w);
    *(ushort4*)(dst + i) = o;
  }
}

// reset ALL channel + canary words to tag 0 — replay safety
__global__ void k_zero_ch(u64* p, int n){
  int i = blockIdx.x*blockDim.x + threadIdx.x;
  if (i < n)
    __hip_atomic_store(p + i, 0ull, __ATOMIC_RELAXED, __HIP_MEMORY_SCOPE_AGENT);
}

// h0 -> hCh slot 0 with tag 1 (+ canaries); c0 -> cyb
__global__ void k_init_state(const float* __restrict__ h0, const float* __restrict__ c0,
                             u64* __restrict__ hCh, u64* __restrict__ hCan,
                             float* __restrict__ cyb){
  int i = blockIdx.x*256 + threadIdx.x; // 65536
  cyb[i] = c0[i];
  if (i < 32768){
    int b = i >> 8, w = i & 255;
    u32 p = (u32)f2bf(h0[b*512 + w*2]) | ((u32)f2bf(h0[b*512 + w*2 + 1]) << 16);
    __hip_atomic_store(hCh + i, ((u64)1 << 32) | p,
                       __ATOMIC_RELAXED, __HIP_MEMORY_SCOPE_AGENT);
  }
  if (i < 256)
    __hip_atomic_store(hCan + i, (u64)1 << 32,
                       __ATOMIC_RELAXED, __HIP_MEMORY_SCOPE_AGENT);
}

// ---------------- precompute GEMM (Xg, gate-interleaved output) ----------------
__global__ __launch_bounds__(256) void k_gemm_bt(
    const float* __restrict__ A, const float* __restrict__ Bm,
    ushort_t* __restrict__ C, int M, int N, int K,
    const float* __restrict__ bias0, const float* __restrict__ bias1){
  __shared__ ushort_t Asm[128][40];
  __shared__ ushort_t Bsm[128][40];
  const int tid = threadIdx.x;
  const int mBase = blockIdx.x*128, nBase = blockIdx.y*128;
  const int l = tid & 63, wv = tid >> 6;
  const int wm = (wv>>1)*64, wn = (wv&1)*64;
  const int lr = l & 15, lq = l >> 4;
  const int srow = tid >> 1, scol = (tid & 1)*16;
  const float* Ap = A + (size_t)(mBase + srow)*K + scol;
  const float* Bp = Bm + (size_t)(nBase + srow)*K + scol;

  f32x4 acc[4][4];
  #pragma unroll
  for (int i=0;i<4;i++)
    #pragma unroll
    for (int j=0;j<4;j++) acc[i][j] = (f32x4)0.f;

  for (int k0 = 0; k0 < K; k0 += 32){
    float4 a0 = *(const float4*)(Ap + k0);
    float4 a1 = *(const float4*)(Ap + k0 + 4);
    float4 a2 = *(const float4*)(Ap + k0 + 8);
    float4 a3 = *(const float4*)(Ap + k0 + 12);
    float4 b0 = *(const float4*)(Bp + k0);
    float4 b1 = *(const float4*)(Bp + k0 + 4);
    float4 b2 = *(const float4*)(Bp + k0 + 8);
    float4 b3 = *(const float4*)(Bp + k0 + 12);
    __syncthreads();
    {
      ushort4 w;
      w.x=f2bf(a0.x); w.y=f2bf(a0.y); w.z=f2bf(a0.z); w.w=f2bf(a0.w);
      *(ushort4*)&Asm[srow][scol+0]  = w;
      w.x=f2bf(a1.x); w.y=f2bf(a1.y); w.z=f2bf(a1.z); w.w=f2bf(a1.w);
      *(ushort4*)&Asm[srow][scol+4]  = w;
      w.x=f2bf(a2.x); w.y=f2bf(a2.y); w.z=f2bf(a2.z); w.w=f2bf(a2.w);
      *(ushort4*)&Asm[srow][scol+8]  = w;
      w.x=f2bf(a3.x); w.y=f2bf(a3.y); w.z=f2bf(a3.z); w.w=f2bf(a3.w);
      *(ushort4*)&Asm[srow][scol+12] = w;
      w.x=f2bf(b0.x); w.y=f2bf(b0.y); w.z=f2bf(b0.z); w.w=f2bf(b0.w);
      *(ushort4*)&Bsm[srow][scol+0]  = w;
      w.x=f2bf(b1.x); w.y=f2bf(b1.y); w.z=f2bf(b1.z); w.w=f2bf(b1.w);
      *(ushort4*)&Bsm[srow][scol+4]  = w;
      w.x=f2bf(b2.x); w.y=f2bf(b2.y); w.z=f2bf(b2.z); w.w=f2bf(b2.w);
      *(ushort4*)&Bsm[srow][scol+8]  = w;
      w.x=f2bf(b3.x); w.y=f2bf(b3.y); w.z=f2bf(b3.z); w.w=f2bf(b3.w);
      *(ushort4*)&Bsm[srow][scol+12] = w;
    }
    __syncthreads();
    short8 aF[4], bF[4];
    #pragma unroll
    for (int i=0;i<4;i++) aF[i] = *(const short8*)&Asm[wm + i*16 + lr][lq*8];
    #pragma unroll
    for (int j=0;j<4;j++) bF[j] = *(const short8*)&Bsm[wn + j*16 + lr][lq*8];
    #pragma unroll
    for (int i=0;i<4;i++)
      #pragma unroll
      for (int j=0;j<4;j++)
        acc[i][j] = MFMA16(aF[i], bF[j], acc[i][j]);
  }

  #pragma unroll
  for (int j=0;j<4;j++){
    int col = nBase + wn + j*16 + lr;
    float bsum = bias0[col] + bias1[col];
    int h = col & 511, gatec = col >> 9;
    #pragma unroll
    for (int i=0;i<4;i++){
      int row0 = mBase + wm + i*16 + lq*4;
      #pragma unroll
      for (int r=0;r<4;r++)
        C[((size_t)(row0+r)*512 + h)*4 + gatec] = f2bf(acc[i][j][r] + bsum);
    }
  }
}

// ---------------- persistent recurrence kernel — canary-gated tagged dataflow ----------------
// Structure identical to R11 (passed); only the sync protocol changed:
// producer: data ch_st -> __syncthreads (vmcnt drained) -> 1 canary ch_st.
// consumer: <=8 threads poll canaries (0.85us backoff) -> one-shot verified reads.

__global__ __launch_bounds__(512) void k_persist(
    const ushort_t* __restrict__ Xg2, const float* __restrict__ ctx,
    const ushort_t* __restrict__ Whb, const ushort_t* __restrict__ Woutb,
    const ushort_t* __restrict__ Winb,
    u64* hCh, u64* hyCh, u64* scCh, u64* wcpCh,
    u64* hCan, u64* hyCan, u64* scCan, u64* wcpCan,
    float* cyb, float* out, float* hf, float* cf)
{
  extern __shared__ __align__(16) char ctx_s[];   // 131072 B: [128 s][512 h] bf16, swizzled

  __shared__ __align__(16) union {
    struct { u32 hstage[4][256]; float gred[4][4][64]; ushort_t pk[4][64]; } a;
    struct { float hy[512]; float tg[512]; float scm[128]; float sc[256];
             float p[256]; float inv; float pad;
             float pacc[8][512]; float wcpm[512]; float wc[512]; ushort_t pk[256]; } b;
  } sh;

  const int pbid = blockIdx.x;
  const int tid = threadIdx.x;
  const int l = tid & 63, wv = tid >> 6;     // 8 waves
  const int lr = l & 15, lq = l >> 4;

  // ---- phase A role: g in [0,32) owns b rows [4g,4g+4); hcq in [0,8) owns 64 h-cols ----
  const int g = pbid >> 3, hcq = pbid & 7;
  const int gate = wv & 3, hv = wv >> 2;          // wave = (gate, col-half)
  // ---- phase B role ----
  const int bB = pbid >> 1, shalf = pbid & 1;     // batch row, s-half (also n-half)
  // pointwise element ids (phase A)
  const int bA = 4*g + ((tid & 255) >> 6), hA = hcq*64 + (tid & 63);

  // ---- one-time: stage ctx[bB, s-half, :] (128 s x 512 h) into LDS, swizzled ----
  {
    const int c4 = (tid & 127)*4;
    #pragma unroll 4
    for (int i = 0; i < 32; ++i){
      int s_loc = i*4 + (tid >> 7);
      float4 v = *(const float4*)(ctx + (((size_t)(shalf*128 + s_loc)*128 + bB)*512) + c4);
      ushort4 o; o.x=f2bf(v.x); o.y=f2bf(v.y); o.z=f2bf(v.z); o.w=f2bf(v.w);
      int boff = (c4*2) ^ ((s_loc & 7) << 4);
      *(ushort4*)(ctx_s + s_loc*1024 + boff) = o;
    }
  }
  __syncthreads();

  ushort4 xq_cur = make_ushort4(0,0,0,0), xq_next = make_ushort4(0,0,0,0);
  if (tid < 256)
    xq_cur = *(const ushort4*)(Xg2 + ((size_t)(bA*T_ + 0)*512 + hA)*4);

  for (int t = 0; t < T_; ++t){
    const int slot = t & (CSLOT-1);
    const u32 tg1 = (u32)(t + 1);

    // ======== Phase A: gates = Xg + h @ Wh^T (M=4 MFMA) ; LSTM pointwise ========
    {
      // canary gate: 8 producers (rows 4g..4g+3 x 2 halves)
      if (tid < 8)
        can_poll(hCan + slot*256 + (4*g + (tid >> 1))*2 + (tid & 1), tg1);
      __syncthreads();
      // one-shot verified load of h tile: 4 rows x 256 words, 2 words/thread
      {
        const int r = tid >> 7, w = (tid*2) & 255;
        const u64* hp = hCh + ((size_t)(slot*128 + 4*g + r)*256) + w;
        u32 w0 = ch_read(hp, tg1);
        u32 w1 = ch_read(hp + 1, tg1);
        sh.a.hstage[r][w]   = w0;
        sh.a.hstage[r][w+1] = w1;
      }
      __syncthreads();
      // MFMA: A-frag rows 0..3 real (rows 4..15 duplicates, outputs ignored)
      f32x4 acc0 = (f32x4)0.f, acc1 = (f32x4)0.f;
      {
        const int n0 = gate*512 + hcq*64 + hv*32 + lr;
        const ushort_t* wp0 = Whb + (size_t)n0*512 + lq*8;
        const ushort_t* wp1 = wp0 + (size_t)16*512;
        const char* hbase = (const char*)sh.a.hstage + (lr & 3)*1024 + lq*16;
        #pragma unroll
        for (int kk = 0; kk < 16; ++kk){
          short8 aF = *(const short8*)(hbase + kk*64);
          short8 b0 = *(const short8*)(wp0 + kk*32);
          short8 b1 = *(const short8*)(wp1 + kk*32);
          acc0 = MFMA16(aF, b0, acc0);
          acc1 = MFMA16(aF, b1, acc1);
        }
      }
      if (lq == 0){
        #pragma unroll
        for (int r = 0; r < 4; ++r){
          sh.a.gred[gate][r][hv*32 + lr]      = acc0[r];
          sh.a.gred[gate][r][hv*32 + 16 + lr] = acc1[r];
        }
      }
      __syncthreads();
      if (tid < 256){
        const int b4 = tid >> 6, hloc = tid & 63;
        float gi  = sh.a.gred[0][b4][hloc] + bf2f(xq_cur.x);
        float gf  = sh.a.gred[1][b4][hloc] + bf2f(xq_cur.y);
        float gg  = sh.a.gred[2][b4][hloc] + bf2f(xq_cur.z);
        float go_ = sh.a.gred[3][b4][hloc] + bf2f(xq_cur.w);
        float co = cyb[bA*512 + hA];
        float cn = sigm(gf)*co + sigm(gi)*tanh_s(gg);
        float hn = sigm(go_)*tanh_s(cn);
        cyb[bA*512 + hA] = cn;
        sh.a.pk[b4][hloc] = f2bf(hn);
        if (t == T_-1) cf[bA*512 + hA] = cn;
      }
      __syncthreads();
      if (tid < 128){
        int r = tid >> 5, wi = tid & 31;
        u32 p = (u32)sh.a.pk[r][wi*2] | ((u32)sh.a.pk[r][wi*2 + 1] << 16);
        ch_st(hyCh + ((size_t)(slot*128 + 4*g + r)*256) + hcq*32 + wi, tg1, p);
      }
      __syncthreads();                      // drain hyCh stores (vmcnt(0))
      if (tid == 0)
        ch_st(hyCan + slot*256 + g*8 + hcq, tg1, 0);
    }

    // ======== Phase B: fused attention + output (batch-stationary) ========
    {
      // prefetch next Xg slice
      if (tid < 256){
        int tn = (t+1 < T_) ? t+1 : t;
        xq_next = *(const ushort4*)(Xg2 + ((size_t)(bA*T_ + tn)*512 + hA)*4);
      }
      // canary gate: 8 hy producers (A-blocks of my cluster)
      if (tid < 8)
        can_poll(hyCan + slot*256 + (bB >> 2)*8 + tid, tg1);
      __syncthreads();
      // hy[bB] one-shot verified
      if (tid < 256){
        u32 p = ch_read(hyCh + ((size_t)(slot*128 + bB)*256) + tid, tg1);
        sh.b.hy[tid*2]   = bf2f((ushort_t)(p & 0xffffu));
        sh.b.hy[tid*2+1] = bf2f((ushort_t)(p >> 16));
      }
      __syncthreads();
      // full target GEMV (redundant per pair): thread j = tid
      {
        const ushort_t* wp = Winb + (size_t)tid*512;
        float d = 0.f;
        #pragma unroll 8
        for (int c = 0; c < 64; ++c){
          short8 w8 = *(const short8*)(wp + c*8);
          #pragma unroll
          for (int e=0;e<8;e++) d += bf2f((ushort_t)w8[e]) * sh.b.hy[c*8 + e];
        }
        sh.b.tg[tid] = d;
      }
      __syncthreads();
      // scores for own s-half: 4 threads per s, 128 h each
      {
        const int s_loc = tid >> 2, q4 = tid & 3;
        const int swz = (s_loc & 7) << 4;
        float d = 0.f;
        #pragma unroll
        for (int c = 0; c < 16; ++c){
          int hb = q4*256 + c*16;                   // byte base in row
          short8 cv = *(const short8*)(ctx_s + s_loc*1024 + (hb ^ swz));
          #pragma unroll
          for (int e=0;e<8;e++) d += bf2f((ushort_t)cv[e]) * sh.b.tg[q4*128 + c*8 + e];
        }
        d += __shfl_xor(d, 1);
        d += __shfl_xor(d, 2);
        if (q4 == 0) sh.b.scm[s_loc] = d;
      }
      __syncthreads();
      // pair-exchange raw scores: store -> canary -> gate -> one-shot
      if (tid < 128)
        ch_st(scCh + (((size_t)(slot*128 + bB)*2 + shalf)*128) + tid,
              tg1, __builtin_bit_cast(u32, sh.b.scm[tid]));
      __syncthreads();                      // drain sc stores
      if (tid == 0){
        ch_st(scCan + slot*256 + bB*2 + shalf, tg1, 0);
        can_poll(scCan + slot*256 + bB*2 + (shalf^1), tg1);
      }
      __syncthreads();
      if (tid < 128){
        u32 p = ch_read(scCh + (((size_t)(slot*128 + bB)*2 + (shalf^1))*128) + tid, tg1);
        sh.b.sc[(shalf^1)*128 + tid] = __builtin_bit_cast(float, p);
        sh.b.sc[shalf*128 + tid]     = sh.b.scm[tid];
      }
      __syncthreads();
      // redundant full softmax (identical in both halves)
      if (wv == 0){
        float v0=sh.b.sc[l], v1=sh.b.sc[l+64], v2=sh.b.sc[l+128], v3=sh.b.sc[l+192];
        float m = fmaxf(fmaxf(v0,v1), fmaxf(v2,v3));
        #pragma unroll
        for (int off=32; off; off>>=1) m = fmaxf(m, __shfl_xor(m, off));
        float e0=__expf(v0-m), e1=__expf(v1-m), e2=__expf(v2-m), e3=__expf(v3-m);
        float s4 = (e0+e1)+(e2+e3);
        #pragma unroll
        for (int off=32; off; off>>=1) s4 += __shfl_xor(s4, off);
        sh.b.p[l]=e0; sh.b.p[l+64]=e1; sh.b.p[l+128]=e2; sh.b.p[l+192]=e3;
        if (l==0) sh.b.inv = 1.f/s4;
      }
      __syncthreads();
      // wc partials over own s-half (full h)
      {
        const int strip = tid >> 6, hg = tid & 63;
        float a8[8];
        #pragma unroll
        for (int e=0;e<8;e++) a8[e]=0.f;
        #pragma unroll
        for (int j = 0; j < 16; ++j){
          int s_loc = strip*16 + j;
          short8 cv = *(const short8*)(ctx_s + s_loc*1024 + ((hg*16) ^ ((s_loc&7)<<4)));
          float pw = sh.b.p[shalf*128 + s_loc];
          #pragma unroll
          for (int e=0;e<8;e++) a8[e] += pw * bf2f((ushort_t)cv[e]);
        }
        #pragma unroll
        for (int e=0;e<8;e++) sh.b.pacc[strip][hg*8+e] = a8[e];
      }
      __syncthreads();
      {
        float s = 0.f;
        #pragma unroll
        for (int st=0;st<8;st++) s += sh.b.pacc[st][tid];
        sh.b.wcpm[tid] = s;
      }
      __syncthreads();
      // pair-exchange wc partials
      if (tid < 256){
        u32 p = (u32)f2bf(sh.b.wcpm[tid*2]) | ((u32)f2bf(sh.b.wcpm[tid*2+1]) << 16);
        ch_st(wcpCh + (((size_t)(slot*128 + bB)*2 + shalf)*256) + tid, tg1, p);
      }
      __syncthreads();                      // drain wcp stores
      if (tid == 0){
        ch_st(wcpCan + slot*256 + bB*2 + shalf, tg1, 0);
        can_poll(wcpCan + slot*256 + bB*2 + (shalf^1), tg1);
      }
      __syncthreads();
      if (tid < 256){
        u32 p = ch_read(wcpCh + (((size_t)(slot*128 + bB)*2 + (shalf^1))*256) + tid, tg1);
        float inv = sh.b.inv;
        sh.b.wc[tid*2]   = (sh.b.wcpm[tid*2]   + bf2f((ushort_t)(p & 0xffffu))) * inv;
        sh.b.wc[tid*2+1] = (sh.b.wcpm[tid*2+1] + bf2f((ushort_t)(p >> 16)))     * inv;
      }
      __syncthreads();
      // output GEMV for own n-half: 2 threads per n (k-split wc | hy)
      {
        const int j2 = tid >> 1, kh = tid & 1;
        const int n = shalf*256 + j2;
        const ushort_t* wp = Woutb + (size_t)n*1024 + kh*512;
        const float* src = kh ? sh.b.hy : sh.b.wc;
        float d = 0.f;
        #pragma unroll 8
        for (int c = 0; c < 64; ++c){
          short8 w8 = *(const short8*)(wp + c*8);
          #pragma unroll
          for (int e=0;e<8;e++) d += bf2f((ushort_t)w8[e]) * src[c*8 + e];
        }
        d += __shfl_xor(d, 1);
        if (kh == 0){
          float v = tanh_s(d);
          out[((size_t)bB*T_ + t)*512 + n] = v;
          sh.b.pk[j2] = f2bf(v);
          if (t == T_-1) hf[bB*512 + n] = v;
        }
      }
      __syncthreads();
      if (tid < 128){
        u32 p = (u32)sh.b.pk[tid*2] | ((u32)sh.b.pk[tid*2+1] << 16);
        ch_st(hCh + ((size_t)(((t+1) & (CSLOT-1))*128 + bB)*256) + shalf*128 + tid,
              (u32)(t + 2), p);
      }
      __syncthreads();                      // drain h stores
      if (tid == 0)
        ch_st(hCan + ((t+1) & (CSLOT-1))*256 + bB*2 + shalf, (u32)(t + 2), 0);
    }
    xq_cur = xq_next;
  }
}

// ---------------- host ----------------

extern "C" void kernel_launch(void* const* d_in, const int* in_sizes, int n_in,
                              void* d_out, int out_size, void* d_ws, size_t ws_size,
                              hipStream_t stream){
  const float* x    = (const float*)d_in[0];
  const float* h0   = (const float*)d_in[1];
  const float* c0   = (const float*)d_in[2];
  const float* ctx  = (const float*)d_in[3];
  const float* Wi   = (const float*)d_in[4];
  const float* bi   = (const float*)d_in[5];
  const float* Wh   = (const float*)d_in[6];
  const float* bh   = (const float*)d_in[7];
  const float* Win  = (const float*)d_in[8];
  const float* Wout = (const float*)d_in[9];

  char* ws = (char*)d_ws;
  ushort_t* Xg2   = (ushort_t*)(ws);                 // 134217728
  ushort_t* Whb   = (ushort_t*)(ws + 134217728);     //   2097152
  ushort_t* Woutb = (ushort_t*)(ws + 136314880);     //   1048576
  ushort_t* Winb  = (ushort_t*)(ws + 137363456);     //    524288
  u64*      hCh   = (u64*)     (ws + 137887744);     //   1048576 (4 slots)
  u64*      hyCh  = (u64*)     (ws + 138936320);     //   1048576
  u64*      scCh  = (u64*)     (ws + 139984896);     //   1048576
  u64*      wcpCh = (u64*)     (ws + 141033472);     //   2097152
  u64*      canB  = (u64*)     (ws + 143130624);     //     32768 (4x 4x256 canaries)
  float*    cyb   = (float*)   (ws + 143163392);     //    262144

  u64* hCan   = canB;
  u64* hyCan  = canB + 1024;
  u64* scCan  = canB + 2048;
  u64* wcpCan = canB + 3072;

  float* out = (float*)d_out;
  float* hf  = out + (size_t)B_*T_*H_;
  float* cf  = hf + (size_t)B_*H_;

  // allow 128 KB dynamic LDS (static ~28 KB + 128 KB < 160 KB/CU)
  hipFuncSetAttribute((const void*)k_persist,
                      hipFuncAttributeMaxDynamicSharedMemorySize, 131072);

  // reset all channel+canary tags (replay safety), then init h0/c0
  k_zero_ch<<<2580, 256, 0, stream>>>(hCh, 659456);  // channels+canaries contiguous
  k_init_state<<<256, 256, 0, stream>>>(h0, c0, hCh, hCan, cyb);

  // converts
  k_cvt_bf16<<<512, 256, 0, stream>>>(Wh, Whb, 4*H_*H_);
  k_cvt_bf16<<<512, 256, 0, stream>>>(Wout, Woutb, H_*2*H_);
  k_cvt_bf16<<<256, 256, 0, stream>>>(Win, Winb, H_*H_);

  // Xg2 = x @ Wi^T + (bi + bh), gate-interleaved [b][t][h][4]
  k_gemm_bt<<<dim3(256,16), 256, 0, stream>>>(x, Wi, Xg2, B_*T_, 4*H_, I_, bi, bh);

  // whole recurrence; canary-gated tagged-channel dataflow
  k_persist<<<256, 512, 131072, stream>>>(Xg2, ctx, Whb, Woutb, Winb,
                                          hCh, hyCh, scCh, wcpCh,
                                          hCan, hyCan, scCan, wcpCan,
                                          cyb, out, hf, cf);
}

// Round 14
// 16706.265 us; speedup vs baseline: 1.0931x; 1.0931x over previous
//
#include <hip/hip_runtime.h>
#include <hip/hip_bf16.h>
#include <stdint.h>

#define B_ 128
#define T_ 256
#define S_ 256
#define I_ 512
#define H_ 512
#define RSLOT 32   // ring depth

typedef __attribute__((ext_vector_type(8))) short short8;
typedef __attribute__((ext_vector_type(4))) float f32x4;
typedef unsigned short ushort_t;
typedef unsigned long long u64;
typedef unsigned int u32;

__device__ __forceinline__ float bf2f(ushort_t u){
  union{ u32 i; float f;} v; v.i = ((u32)u)<<16; return v.f;
}
__device__ __forceinline__ ushort_t f2bf(float f){
  union{ u32 i; float f;} v; v.f=f;
  u32 x=v.i; u32 r = x + 0x7fffu + ((x>>16)&1u);
  return (ushort_t)(r>>16);
}
__device__ __forceinline__ float sigm(float x){ return 1.f/(1.f + __expf(-x)); }
__device__ __forceinline__ float tanh_s(float x){
  float a = fabsf(x);
  float e = __expf(-2.f*a);
  float t = (1.f - e)/(1.f + e);
  return x < 0.f ? -t : t;
}

__device__ __forceinline__ f32x4 MFMA16(short8 a, short8 b, f32x4 c){
  typedef __attribute__((ext_vector_type(8))) __bf16 bf16x8;
  return __builtin_amdgcn_mfma_f32_16x16x32_bf16(
      __builtin_bit_cast(bf16x8, a), __builtin_bit_cast(bf16x8, b), c, 0, 0, 0);
}

// fabric (agent-scope) 8B store; visibility ordered by the full flat barrier
__device__ __forceinline__ void fab_store_u64(void* p, u64 v){
  __hip_atomic_store((u64*)p, v, __ATOMIC_RELAXED, __HIP_MEMORY_SCOPE_AGENT);
}

// ---------------- converts / init ----------------

__global__ void k_cvt_bf16(const float* __restrict__ src, ushort_t* __restrict__ dst, int n){
  int i = (blockIdx.x*blockDim.x + threadIdx.x)*4;
  int stride = gridDim.x*blockDim.x*4;
  for (; i < n; i += stride){
    float4 v = *(const float4*)(src + i);
    ushort4 o; o.x=f2bf(v.x); o.y=f2bf(v.y); o.z=f2bf(v.z); o.w=f2bf(v.w);
    *(ushort4*)(dst + i) = o;
  }
}

__global__ void k_init_state(const float* __restrict__ h0, const float* __restrict__ c0,
                             ushort_t* __restrict__ hring0, float* __restrict__ cyb){
  int i = blockIdx.x*blockDim.x + threadIdx.x; // 65536
  hring0[i] = f2bf(h0[i]);
  cyb[i] = c0[i];
}

__global__ void k_zero_bar(int* f){
  if (threadIdx.x < 256) f[threadIdx.x] = 0;
}

// ---------------- precompute GEMM (Xg, gate-interleaved output) ----------------
// Xg2[((b*T+t)*512 + h)*4 + gate] = (x @ Wi^T + bi + bh)
__global__ __launch_bounds__(256) void k_gemm_bt(
    const float* __restrict__ A, const float* __restrict__ Bm,
    ushort_t* __restrict__ C, int M, int N, int K,
    const float* __restrict__ bias0, const float* __restrict__ bias1){
  __shared__ ushort_t Asm[128][40];
  __shared__ ushort_t Bsm[128][40];
  const int tid = threadIdx.x;
  const int mBase = blockIdx.x*128, nBase = blockIdx.y*128;
  const int l = tid & 63, wv = tid >> 6;
  const int wm = (wv>>1)*64, wn = (wv&1)*64;
  const int lr = l & 15, lq = l >> 4;
  const int srow = tid >> 1, scol = (tid & 1)*16;
  const float* Ap = A + (size_t)(mBase + srow)*K + scol;
  const float* Bp = Bm + (size_t)(nBase + srow)*K + scol;

  f32x4 acc[4][4];
  #pragma unroll
  for (int i=0;i<4;i++)
    #pragma unroll
    for (int j=0;j<4;j++) acc[i][j] = (f32x4)0.f;

  for (int k0 = 0; k0 < K; k0 += 32){
    float4 a0 = *(const float4*)(Ap + k0);
    float4 a1 = *(const float4*)(Ap + k0 + 4);
    float4 a2 = *(const float4*)(Ap + k0 + 8);
    float4 a3 = *(const float4*)(Ap + k0 + 12);
    float4 b0 = *(const float4*)(Bp + k0);
    float4 b1 = *(const float4*)(Bp + k0 + 4);
    float4 b2 = *(const float4*)(Bp + k0 + 8);
    float4 b3 = *(const float4*)(Bp + k0 + 12);
    __syncthreads();
    {
      ushort4 w;
      w.x=f2bf(a0.x); w.y=f2bf(a0.y); w.z=f2bf(a0.z); w.w=f2bf(a0.w);
      *(ushort4*)&Asm[srow][scol+0]  = w;
      w.x=f2bf(a1.x); w.y=f2bf(a1.y); w.z=f2bf(a1.z); w.w=f2bf(a1.w);
      *(ushort4*)&Asm[srow][scol+4]  = w;
      w.x=f2bf(a2.x); w.y=f2bf(a2.y); w.z=f2bf(a2.z); w.w=f2bf(a2.w);
      *(ushort4*)&Asm[srow][scol+8]  = w;
      w.x=f2bf(a3.x); w.y=f2bf(a3.y); w.z=f2bf(a3.z); w.w=f2bf(a3.w);
      *(ushort4*)&Asm[srow][scol+12] = w;
      w.x=f2bf(b0.x); w.y=f2bf(b0.y); w.z=f2bf(b0.z); w.w=f2bf(b0.w);
      *(ushort4*)&Bsm[srow][scol+0]  = w;
      w.x=f2bf(b1.x); w.y=f2bf(b1.y); w.z=f2bf(b1.z); w.w=f2bf(b1.w);
      *(ushort4*)&Bsm[srow][scol+4]  = w;
      w.x=f2bf(b2.x); w.y=f2bf(b2.y); w.z=f2bf(b2.z); w.w=f2bf(b2.w);
      *(ushort4*)&Bsm[srow][scol+8]  = w;
      w.x=f2bf(b3.x); w.y=f2bf(b3.y); w.z=f2bf(b3.z); w.w=f2bf(b3.w);
      *(ushort4*)&Bsm[srow][scol+12] = w;
    }
    __syncthreads();
    short8 aF[4], bF[4];
    #pragma unroll
    for (int i=0;i<4;i++) aF[i] = *(const short8*)&Asm[wm + i*16 + lr][lq*8];
    #pragma unroll
    for (int j=0;j<4;j++) bF[j] = *(const short8*)&Bsm[wn + j*16 + lr][lq*8];
    #pragma unroll
    for (int i=0;i<4;i++)
      #pragma unroll
      for (int j=0;j<4;j++)
        acc[i][j] = MFMA16(aF[i], bF[j], acc[i][j]);
  }

  #pragma unroll
  for (int j=0;j<4;j++){
    int col = nBase + wn + j*16 + lr;
    float bsum = bias0[col] + bias1[col];
    int h = col & 511, gatec = col >> 9;
    #pragma unroll
    for (int i=0;i<4;i++){
      int row0 = mBase + wm + i*16 + lq*4;
      #pragma unroll
      for (int r=0;r<4;r++)
        C[((size_t)(row0+r)*512 + h)*4 + gatec] = f2bf(acc[i][j][r] + bsum);
    }
  }
}

// ---------------- flat grid barrier (R7-proven) ----------------
__device__ __forceinline__ void gbar(int* flags, int gen){
  __syncthreads();
  const int tid = threadIdx.x;
  if (tid == 0)
    __hip_atomic_store(&flags[blockIdx.x], gen, __ATOMIC_RELAXED, __HIP_MEMORY_SCOPE_AGENT);
  if (tid < 256){
    while (__hip_atomic_load(&flags[tid], __ATOMIC_RELAXED, __HIP_MEMORY_SCOPE_AGENT) < gen)
      __builtin_amdgcn_s_sleep(2);
  }
  __syncthreads();
  asm volatile("" ::: "memory");
}

// ---------------- persistent recurrence kernel ----------------
// 3 phases/step, flat barriers:
//  A  [role (bm,hc)]: gates = Xg + h@Wh^T (reg-pinned Wh), pointwise -> hyring
//  B1 [role (b,half)]: tg GEMV, own-s-half scores, LOCAL softmax, wc-partial -> rings
//  B2 [role (b,half)]: flash-combine halves, out GEMV (n-half) -> out, hring

__global__ __launch_bounds__(512) void k_persist(
    const ushort_t* __restrict__ Xg2, const float* __restrict__ ctx,
    const ushort_t* __restrict__ Whb, const ushort_t* __restrict__ Woutb,
    const ushort_t* __restrict__ Winb,
    ushort_t* hring, ushort_t* hyring, ushort_t* wcpring, float* mlring,
    float* cyb, float* out, float* hf, float* cf,
    int* flags)
{
  extern __shared__ __align__(16) char ctx_s[];   // 131072 B: [128 s][512 h] bf16, swizzled

  __shared__ __align__(16) union {
    struct { float red[8][256]; ushort_t pk[256]; } a;
    struct { float hy[512]; float tg[512]; float sc[128]; float p[128];
             float mo, lo;
             float pacc[8][512]; float wcpm[512]; float wc[512]; ushort_t pk[256]; } b;
  } sh;

  const int pbid = blockIdx.x;
  const int tid = threadIdx.x;
  const int l = tid & 63, wv = tid >> 6;     // 8 waves
  const int lr = l & 15, lq = l >> 4;

  // ---- phase A role ----
  const int bm = pbid >> 5, hc = pbid & 31;
  const int gate = wv & 3, khalf = wv >> 2;
  short8 whr[8];
  #pragma unroll
  for (int kk=0;kk<8;kk++)
    whr[kk] = *(const short8*)(Whb + (size_t)(gate*512 + hc*16 + lr)*512
                               + khalf*256 + lq*8 + kk*32);
  // ---- phase B role ----
  const int bB = pbid >> 1, half = pbid & 1;     // batch row, s-half (= n-half)
  // phase A pointwise element
  const int bA = bm*16 + ((tid & 255) >> 4), hA = hc*16 + (tid & 15);

  // ---- one-time: stage ctx[bB, half, :] (128 s x 512 h) into LDS, swizzled ----
  {
    const int c4 = (tid & 127)*4;
    #pragma unroll 4
    for (int i = 0; i < 32; ++i){
      int s_loc = i*4 + (tid >> 7);
      float4 v = *(const float4*)(ctx + (((size_t)(half*128 + s_loc)*128 + bB)*512) + c4);
      ushort4 o; o.x=f2bf(v.x); o.y=f2bf(v.y); o.z=f2bf(v.z); o.w=f2bf(v.w);
      int boff = (c4*2) ^ ((s_loc & 7) << 4);
      *(ushort4*)(ctx_s + s_loc*1024 + boff) = o;
    }
  }
  __syncthreads();

  ushort4 xq_cur = make_ushort4(0,0,0,0), xq_next = make_ushort4(0,0,0,0);
  if (tid < 256)
    xq_cur = *(const ushort4*)(Xg2 + ((size_t)(bA*T_ + 0)*512 + hA)*4);

  int gen = 0;
  for (int t = 0; t < T_; ++t){
    const size_t slotC = (size_t)(t & (RSLOT-1)) * 65536;
    const int slotI = t & (RSLOT-1);

    // ======== Phase A: gates = Xg[:,t,:] + h @ Wh^T ; LSTM pointwise ========
    {
      float co = 0.f;
      if (tid < 256) co = cyb[bA*512 + hA];
      f32x4 acc = (f32x4)0.f;
      const ushort_t* ap = hring + slotC + (size_t)(bm*16 + lr)*512 + khalf*256 + lq*8;
      short8 hv8[8];
      #pragma unroll
      for (int kk=0;kk<8;kk++) hv8[kk] = *(const short8*)(ap + kk*32);
      #pragma unroll
      for (int kk=0;kk<8;kk++) acc = MFMA16(hv8[kk], whr[kk], acc);
      #pragma unroll
      for (int r=0;r<4;r++) sh.a.red[wv][(lq*4+r)*16+lr] = acc[r];
      __syncthreads();
      if (tid < 256){
        float gi  = sh.a.red[0][tid] + sh.a.red[4][tid] + bf2f(xq_cur.x);
        float gf  = sh.a.red[1][tid] + sh.a.red[5][tid] + bf2f(xq_cur.y);
        float gg  = sh.a.red[2][tid] + sh.a.red[6][tid] + bf2f(xq_cur.z);
        float go_ = sh.a.red[3][tid] + sh.a.red[7][tid] + bf2f(xq_cur.w);
        float cn = sigm(gf)*co + sigm(gi)*tanh_s(gg);
        float hn = sigm(go_)*tanh_s(cn);
        cyb[bA*512 + hA] = cn;
        sh.a.pk[tid] = f2bf(hn);
        if (t == T_-1) cf[bA*512 + hA] = cn;
      }
      __syncthreads();
      if (tid < 64){
        u64 v = *(u64*)&sh.a.pk[tid*4];
        fab_store_u64(hyring + slotC + (size_t)(bm*16 + (tid>>2))*512
                      + hc*16 + (tid&3)*4, v);
      }
    }
    gbar(flags, ++gen);

    // ======== Phase B1: tg GEMV + own-half scores + local softmax + wc-partial ========
    {
      // prefetch next step's Xg slice
      if (tid < 256){
        int tn = (t+1 < T_) ? t+1 : t;
        xq_next = *(const ushort4*)(Xg2 + ((size_t)(bA*T_ + tn)*512 + hA)*4);
      }
      // hy[bB] -> LDS (plain read after full barrier)
      if (tid < 128){
        ushort4 v = *(const ushort4*)(hyring + slotC + (size_t)bB*512 + tid*4);
        sh.b.hy[tid*4+0]=bf2f(v.x); sh.b.hy[tid*4+1]=bf2f(v.y);
        sh.b.hy[tid*4+2]=bf2f(v.z); sh.b.hy[tid*4+3]=bf2f(v.w);
      }
      __syncthreads();
      // full tg = hy @ Win^T (redundant per pair, identical fp ops)
      {
        const ushort_t* wp = Winb + (size_t)tid*512;
        float d = 0.f;
        #pragma unroll 8
        for (int c = 0; c < 64; ++c){
          short8 w8 = *(const short8*)(wp + c*8);
          #pragma unroll
          for (int e=0;e<8;e++) d += bf2f((ushort_t)w8[e]) * sh.b.hy[c*8 + e];
        }
        sh.b.tg[tid] = d;
      }
      __syncthreads();
      // scores for own s-half: 4 threads per s, 128 h each
      {
        const int s_loc = tid >> 2, q4 = tid & 3;
        const int swz = (s_loc & 7) << 4;
        float d = 0.f;
        #pragma unroll
        for (int c = 0; c < 16; ++c){
          int hb = q4*256 + c*16;
          short8 cv = *(const short8*)(ctx_s + s_loc*1024 + (hb ^ swz));
          #pragma unroll
          for (int e=0;e<8;e++) d += bf2f((ushort_t)cv[e]) * sh.b.tg[q4*128 + c*8 + e];
        }
        d += __shfl_xor(d, 1);
        d += __shfl_xor(d, 2);
        if (q4 == 0) sh.b.sc[s_loc] = d;
      }
      __syncthreads();
      // local softmax over own 128 scores (wave 0)
      if (wv == 0){
        float v0 = sh.b.sc[l], v1 = sh.b.sc[l+64];
        float m = fmaxf(v0, v1);
        #pragma unroll
        for (int off=32; off; off>>=1) m = fmaxf(m, __shfl_xor(m, off));
        float e0 = __expf(v0 - m), e1 = __expf(v1 - m);
        float s2 = e0 + e1;
        #pragma unroll
        for (int off=32; off; off>>=1) s2 += __shfl_xor(s2, off);
        sh.b.p[l] = e0; sh.b.p[l+64] = e1;
        if (l == 0){ sh.b.mo = m; sh.b.lo = s2; }
      }
      __syncthreads();
      // wc-partial over own s-half (full h)
      {
        const int strip = tid >> 6, hg = tid & 63;
        float a8[8];
        #pragma unroll
        for (int e=0;e<8;e++) a8[e]=0.f;
        #pragma unroll
        for (int j = 0; j < 16; ++j){
          int s_loc = strip*16 + j;
          short8 cv = *(const short8*)(ctx_s + s_loc*1024 + ((hg*16) ^ ((s_loc&7)<<4)));
          float pw = sh.b.p[s_loc];
          #pragma unroll
          for (int e=0;e<8;e++) a8[e] += pw * bf2f((ushort_t)cv[e]);
        }
        #pragma unroll
        for (int e=0;e<8;e++) sh.b.pacc[strip][hg*8+e] = a8[e];
      }
      __syncthreads();
      {
        float s = 0.f;
        #pragma unroll
        for (int st=0;st<8;st++) s += sh.b.pacc[st][tid];
        sh.b.wcpm[tid] = s;
      }
      __syncthreads();
      // ship wc-partial (bf16) + (m,l) through rings; barrier orders visibility
      if (tid < 128){
        ushort4 w;
        w.x = f2bf(sh.b.wcpm[tid*4+0]); w.y = f2bf(sh.b.wcpm[tid*4+1]);
        w.z = f2bf(sh.b.wcpm[tid*4+2]); w.w = f2bf(sh.b.wcpm[tid*4+3]);
        fab_store_u64(wcpring + (((size_t)(slotI*128 + bB)*2 + half)*512) + tid*4,
                      __builtin_bit_cast(u64, w));
      }
      if (tid == 128){
        float2 ml = make_float2(sh.b.mo, sh.b.lo);
        fab_store_u64(mlring + (((size_t)(slotI*128 + bB)*2 + half)*2),
                      __builtin_bit_cast(u64, ml));
      }
    }
    gbar(flags, ++gen);

    // ======== Phase B2: flash-combine + out GEMV ========
    {
      // partner (m,l); combine factors computed redundantly by all threads
      float2 mlp = *(const float2*)(mlring + (((size_t)(slotI*128 + bB)*2 + (half^1))*2));
      float m  = fmaxf(sh.b.mo, mlp.x);
      float ao = __expf(sh.b.mo - m), ap_ = __expf(mlp.x - m);
      float inv = 1.f / (ao*sh.b.lo + ap_*mlp.y);
      // partner wc-partial (plain read) + combine
      {
        const ushort_t* wpp = wcpring + (((size_t)(slotI*128 + bB)*2 + (half^1))*512);
        sh.b.wc[tid] = (ao*sh.b.wcpm[tid] + ap_*bf2f(wpp[tid])) * inv;
      }
      __syncthreads();
      // out GEMV for own n-half: 2 threads per n (k-split: wc | hy)
      {
        const int j2 = tid >> 1, kh = tid & 1;
        const int n = half*256 + j2;
        const ushort_t* wp = Woutb + (size_t)n*1024 + kh*512;
        const float* src = kh ? sh.b.hy : sh.b.wc;
        float d = 0.f;
        #pragma unroll 8
        for (int c = 0; c < 64; ++c){
          short8 w8 = *(const short8*)(wp + c*8);
          #pragma unroll
          for (int e=0;e<8;e++) d += bf2f((ushort_t)w8[e]) * src[c*8 + e];
        }
        d += __shfl_xor(d, 1);
        if (kh == 0){
          float v = tanh_s(d);
          out[((size_t)bB*T_ + t)*512 + n] = v;
          sh.b.pk[j2] = f2bf(v);
          if (t == T_-1) hf[bB*512 + n] = v;
        }
      }
      __syncthreads();
      if (tid < 64){
        u64 v = *(u64*)&sh.b.pk[tid*4];
        size_t slotN = (size_t)((t+1) & (RSLOT-1)) * 65536;
        fab_store_u64(hring + slotN + (size_t)bB*512 + half*256 + tid*4, v);
      }
    }
    gbar(flags, ++gen);
    xq_cur = xq_next;
  }
}

// ---------------- host ----------------

extern "C" void kernel_launch(void* const* d_in, const int* in_sizes, int n_in,
                              void* d_out, int out_size, void* d_ws, size_t ws_size,
                              hipStream_t stream){
  const float* x    = (const float*)d_in[0];
  const float* h0   = (const float*)d_in[1];
  const float* c0   = (const float*)d_in[2];
  const float* ctx  = (const float*)d_in[3];
  const float* Wi   = (const float*)d_in[4];
  const float* bi   = (const float*)d_in[5];
  const float* Wh   = (const float*)d_in[6];
  const float* bh   = (const float*)d_in[7];
  const float* Win  = (const float*)d_in[8];
  const float* Wout = (const float*)d_in[9];

  char* ws = (char*)d_ws;
  ushort_t* Xg2     = (ushort_t*)(ws);                 // 134217728
  ushort_t* Whb     = (ushort_t*)(ws + 134217728);     //   2097152
  ushort_t* Woutb   = (ushort_t*)(ws + 136314880);     //   1048576
  ushort_t* Winb    = (ushort_t*)(ws + 137363456);     //    524288
  ushort_t* hring   = (ushort_t*)(ws + 137887744);     //   4194304 (32 slots)
  ushort_t* hyring  = (ushort_t*)(ws + 142082048);     //   4194304
  ushort_t* wcpring = (ushort_t*)(ws + 146276352);     //   8388608 (32x128x2x512 bf16)
  float*    mlring  = (float*)   (ws + 154664960);     //     65536
  float*    cyb     = (float*)   (ws + 154730496);     //    262144
  int*      flags   = (int*)     (ws + 154992640);     //      1024

  float* out = (float*)d_out;
  float* hf  = out + (size_t)B_*T_*H_;
  float* cf  = hf + (size_t)B_*H_;

  // allow 128 KB dynamic LDS (static ~26 KB + 128 KB < 160 KB/CU)
  hipFuncSetAttribute((const void*)k_persist,
                      hipFuncAttributeMaxDynamicSharedMemorySize, 131072);

  // reset barrier state (replay safety); init h0/c0
  k_zero_bar<<<1, 256, 0, stream>>>(flags);
  k_init_state<<<256, 256, 0, stream>>>(h0, c0, hring, cyb);

  // converts
  k_cvt_bf16<<<512, 256, 0, stream>>>(Wh, Whb, 4*H_*H_);
  k_cvt_bf16<<<512, 256, 0, stream>>>(Wout, Woutb, H_*2*H_);
  k_cvt_bf16<<<256, 256, 0, stream>>>(Win, Winb, H_*H_);

  // Xg2 = x @ Wi^T + (bi + bh), gate-interleaved [b][t][h][4]
  k_gemm_bt<<<dim3(256,16), 256, 0, stream>>>(x, Wi, Xg2, B_*T_, 4*H_, I_, bi, bh);

  // whole recurrence; 3 flat barriers/step, flash-combined attention
  k_persist<<<256, 512, 131072, stream>>>(Xg2, ctx, Whb, Woutb, Winb,
                                          hring, hyring, wcpring, mlring,
                                          cyb, out, hf, cf,
                                          flags);
}